// Round 8
// baseline (597.652 us; speedup 1.0000x reference)
//
#include <hip/hip_runtime.h>

// Balanced sinkhorn, persistent kernel, round 8: 3-hop sync.
//  - Stage 1 flagless done right: reducers burst-load all 15 partials
//    unconditionally (independent loads, one latency), OR the NaN bits,
//    retry-all. Detect == read. (R6 failed because its round-robin made the
//    15 checks DEPENDENT.)
//  - Private mailboxes: reducers scatter results into each worker's own
//    mailbox row (coalesced); workers poll their OWN line (sole reader).
//    fin replicas + their 240-reader congestion are gone.
//  - Zero __syncthreads in the worker sync path; all store-drain ordering
//    rides on poll vmcnt(0) waits and the phase-math barriers.
// P is 2-parity + QN invalidation (reducer-read gating); mailbox is single
// copy (reducer-write gating via worker's publish). Phase math / replicated
// optimizer identical to R3-R7 (validated, absmax 2.4e-4).

namespace {

constexpr int KDIM = 256;
constexpr int NBLK = 256;
constexpr int NRED = 16;    // dedicated reducer blocks
constexpr int NW   = 240;   // worker blocks
constexpr int RMAX = 69;    // max rows per worker
constexpr float L2E20 = 28.853900817779268f;  // 20 * log2(e)

// ws layout (doubles): P[2][240][512] | MB[240][512]
constexpr size_t P_DBL  = 2ull * NW * 512;   // 245760
constexpr size_t MB_OFF = P_DBL;
constexpr size_t MB_DBL = (size_t)NW * 512;  // 122880
constexpr size_t WS_DBL = P_DBL + MB_DBL;    // 368640 (2.95 MB)

__device__ __forceinline__ double fast_exp_d(double x) {
  const double LOG2E  = 1.4426950408889634074;
  const double LN2_HI = 6.93147180369123816490e-01;
  const double LN2_LO = 1.90821492927058770002e-10;
  double n = rint(x * LOG2E);
  double t = fma(-n, LN2_HI, x);
  t = fma(-n, LN2_LO, t);
  double p = 2.4801587301587302e-05;
  p = fma(p, t, 1.9841269841269841e-04);
  p = fma(p, t, 1.3888888888888889e-03);
  p = fma(p, t, 8.3333333333333333e-03);
  p = fma(p, t, 4.1666666666666664e-02);
  p = fma(p, t, 1.6666666666666666e-01);
  p = fma(p, t, 0.5);
  p = fma(p, t, 1.0);
  p = fma(p, t, 1.0);
  long long ni = (long long)n;
  double s = __longlong_as_double((unsigned long long)(ni + 1023LL) << 52);
  return p * s;
}

__device__ __forceinline__ double wave_sum_d(double v) {
#pragma unroll
  for (int o = 32; o > 0; o >>= 1) v += __shfl_down(v, o);
  return v;
}
__device__ __forceinline__ double wave_max_d(double v) {
#pragma unroll
  for (int o = 32; o > 0; o >>= 1) v = fmax(v, __shfl_down(v, o));
  return v;
}

__device__ __forceinline__ double pload(const double* p) {
  return __hip_atomic_load(p, __ATOMIC_RELAXED, __HIP_MEMORY_SCOPE_AGENT);
}
__device__ __forceinline__ void pstore(double* p, double v) {
  __hip_atomic_store(p, v, __ATOMIC_RELAXED, __HIP_MEMORY_SCOPE_AGENT);
}

}  // namespace

// ---------------------------------------------------------------------------
__global__ __launch_bounds__(256) void kInitWS(double* __restrict__ ws) {
  const double QN = __builtin_nan("");
  size_t gid = (size_t)blockIdx.x * 256 + threadIdx.x;
  size_t stride = (size_t)gridDim.x * 256;
  for (size_t j = gid; j < WS_DBL; j += stride) ws[j] = QN;
}

// ---------------------------------------------------------------------------
__global__ __launch_bounds__(256, 1) void sink_main(
    const float* __restrict__ feat, const float* __restrict__ w_in,
    float* __restrict__ out, double* __restrict__ ws) {
  __shared__ float  Et[RMAX * KDIM];   // 69 KB
  __shared__ float  Ft[RMAX * KDIM];   // 69 KB
  __shared__ double alpha[KDIM];
  __shared__ double tmp1[KDIM];        // reducer fold
  __shared__ double tmp2[KDIM];
  __shared__ double sfin[32];
  __shared__ double v1s[RMAX], v2s[RMAX], v3s[RMAX];
  __shared__ double grow[RMAX], wrow[RMAX], sbr[RMAX];
  __shared__ float  mrow[RMAX];
  __shared__ double sred[8];

  const int t = threadIdx.x, bid = blockIdx.x;
  const int wv = t >> 6, lane = t & 63;
  const double QN = __builtin_nan("");

  double* P  = ws;
  double* MB = ws + MB_OFF;

  // ======================= REDUCER PATH (blocks 0..15) =====================
  if (bid < NRED) {
    const int rep = t >> 4, c = t & 15;
    const int k = bid * 16 + c;

    auto do_reduce = [&](unsigned ph, bool pair) {
      const int q = ph & 1;
      const double* base = P + (size_t)q * NW * 512;
      double s1 = 0.0, s2 = 0.0;
      if (pair) {
        double va[15], vb[15];
        for (;;) {
          bool bad = false;
#pragma unroll
          for (int i = 0; i < 15; ++i) {
            const double* rr = base + (size_t)(rep + 16 * i) * 512 + k;
            va[i] = pload(rr);
            vb[i] = pload(rr + 256);
          }
#pragma unroll
          for (int i = 0; i < 15; ++i)
            bad |= __builtin_isnan(va[i]) || __builtin_isnan(vb[i]);
          if (!bad) break;
          __builtin_amdgcn_s_sleep(2);
        }
#pragma unroll
        for (int i = 0; i < 15; ++i) { s1 += va[i]; s2 += vb[i]; }
      } else {
        double va[15];
        for (;;) {
          bool bad = false;
#pragma unroll
          for (int i = 0; i < 15; ++i)
            va[i] = pload(base + (size_t)(rep + 16 * i) * 512 + k);
#pragma unroll
          for (int i = 0; i < 15; ++i) bad |= __builtin_isnan(va[i]);
          if (!bad) break;
          __builtin_amdgcn_s_sleep(2);
        }
#pragma unroll
        for (int i = 0; i < 15; ++i) s1 += va[i];
      }
      tmp1[t] = s1;
      if (pair) tmp2[t] = s2;
      __syncthreads();
      if (t < 16) {
        double s = 0.0;
#pragma unroll
        for (int g = 0; g < 16; ++g) s += tmp1[g * 16 + t];
        sfin[t] = s;
      } else if (pair && t < 32) {
        const int c2 = t - 16;
        double s = 0.0;
#pragma unroll
        for (int g = 0; g < 16; ++g) s += tmp2[g * 16 + c2];
        sfin[16 + c2] = s;
      }
      __syncthreads();
      // scatter result into every worker's mailbox (coalesced 16-thread lines)
      const double o1 = sfin[c];
      const double o2 = pair ? sfin[16 + c] : 0.0;
#pragma unroll
      for (int i = 0; i < 15; ++i) {
        double* mb = MB + (size_t)(rep + 16 * i) * 512 + k;
        pstore(mb, o1);
        if (pair) pstore(mb + 256, o2);
      }
      // sfin WAR vs next round handled by next round's fold barrier
    };

    unsigned ph = 1;
    do_reduce(ph, false);                       // u0
    for (int it = 0; it < 9; ++it) {
      ++ph; do_reduce(ph, false);               // u1
      ++ph; do_reduce(ph, false);               // u2
      ++ph; do_reduce(ph, true);                // (gdir,t3)
      ++ph; do_reduce(ph, false);               // ga2
      ++ph; do_reduce(ph, false);               // ga1
    }
    ++ph; do_reduce(ph, false);                 // u1 (it=9)
    ++ph; do_reduce(ph, false);                 // u2 (it=9)
    return;
  }

  // ======================= WORKER PATH (blocks 16..255) ====================
  const int wid = bid - NRED;
  const int nr = (wid < 64) ? 69 : 68;
  const int start = (wid < 64) ? wid * 69 : 4416 + (wid - 64) * 68;

  auto blk_sum = [&](double v) -> double {
    v = wave_sum_d(v);
    __syncthreads();
    if (lane == 0) sred[wv] = v;
    __syncthreads();
    return sred[0] + sred[1] + sred[2] + sred[3];
  };
  auto blk_max = [&](double v) -> double {
    v = wave_max_d(v);
    __syncthreads();
    if (lane == 0) sred[wv + 4] = v;
    __syncthreads();
    return fmax(fmax(sred[4], sred[5]), fmax(sred[6], sred[7]));
  };

  // publish partial; poll OWN mailbox line; invalidate mailbox + P row.
  // NO barrier: every caller hits a __syncthreads (phase math) before the
  // next publish, which drains the QN stores (vmcnt(0) before s_barrier).
  auto w_allreduce = [&](unsigned ph, bool pair, double pa, double pb,
                         double& r1, double& r2) {
    const int q = ph & 1;
    double* row = P + ((size_t)q * NW + wid) * 512;
    pstore(&row[t], pa);
    if (pair) pstore(&row[256 + t], pb);
    double* mb = MB + (size_t)wid * 512;
    for (;;) {
      double a = pload(&mb[t]);
      if (!__builtin_isnan(a)) { r1 = a; break; }
      __builtin_amdgcn_s_sleep(2);
    }
    if (pair) {
      for (;;) {
        double b2 = pload(&mb[256 + t]);
        if (!__builtin_isnan(b2)) { r2 = b2; break; }
        __builtin_amdgcn_s_sleep(2);
      }
    }
    // poll loads' vmcnt(0) waits ordered the publish stores before these:
    pstore(&mb[t], QN);
    pstore(&mb[256 + t], QN);
    pstore(&row[t], QN);
    if (pair) pstore(&row[256 + t], QN);
  };

  auto row_pass = [&](double* dstv) {
    double a0 = alpha[4 * lane + 0], a1 = alpha[4 * lane + 1];
    double a2 = alpha[4 * lane + 2], a3 = alpha[4 * lane + 3];
    for (int r = wv; r < nr; r += 4) {
      float4 e4 = ((const float4*)(Et + r * KDIM))[lane];
      double s1 = a0 * (double)e4.x + a1 * (double)e4.y +
                  a2 * (double)e4.z + a3 * (double)e4.w;
      s1 = wave_sum_d(s1);
      if (lane == 0) dstv[r] = s1;
    }
  };
  auto col_partial = [&]() -> double {
    double a = 0.0;
#pragma unroll 4
    for (int r = 0; r < nr; ++r) a += (double)Et[r * KDIM + t] * wrow[r];
    return a;
  };

  // ---- setup
  {
    const float4* src = (const float4*)(feat + (size_t)start * KDIM);
    float4* dst = (float4*)Ft;
    const int total4 = nr * 64;
    for (int s = t; s < total4; s += 256) dst[s] = src[s];
  }
  __syncthreads();
  for (int r = wv; r < nr; r += 4) {
    float4 f4 = ((const float4*)(Ft + r * KDIM))[lane];
    float m = fmaxf(fmaxf(f4.x, f4.y), fmaxf(f4.z, f4.w));
#pragma unroll
    for (int o = 32; o > 0; o >>= 1) m = fmaxf(m, __shfl_down(m, o));
    if (lane == 0) {
      mrow[r] = m;
      sbr[r] = fast_exp_d(20.0 * (double)m);
    }
  }
  __syncthreads();
  double pu0 = 0.0;
#pragma unroll 4
  for (int r = 0; r < nr; ++r) {
    float e = exp2f((Ft[r * KDIM + t] - mrow[r]) * L2E20);
    Et[r * KDIM + t] = e;
    pu0 += (double)e * sbr[r];
  }
  float w_t = w_in[t], buf_t = 0.0f;
  double k2_t;
  {
    double x = (double)w_t;
    double m = blk_max(x);
    double e = fast_exp_d(x - m);
    double s = blk_sum(e);
    k2_t = e / s;
  }
  unsigned ph = 1;
  double u0_t, dmy;
  w_allreduce(ph, false, pu0, 0.0, u0_t, dmy);

  // ---- outer loop
  for (int it = 0; it < 10; ++it) {
    double u1_t, u2_t;

    // A: v1~, allreduce u1
    alpha[t] = k2_t / u0_t;
    __syncthreads();
    row_pass(v1s);
    __syncthreads();
    if (t < nr) wrow[t] = 1.0 / (16384.0 * v1s[t]);
    __syncthreads();
    { double pa = col_partial(); ++ph; w_allreduce(ph, false, pa, 0.0, u1_t, dmy); }

    // B: v2~, allreduce u2
    alpha[t] = k2_t / u1_t;
    __syncthreads();
    row_pass(v2s);
    __syncthreads();
    if (t < nr) wrow[t] = 1.0 / (16384.0 * v2s[t]);
    __syncthreads();
    { double pa = col_partial(); ++ph; w_allreduce(ph, false, pa, 0.0, u2_t, dmy); }

    if (it == 9) {
      // output: Q[b,k] = alpha3[k]*E~[r,k]/v3~[b]
      alpha[t] = k2_t / u2_t;
      __syncthreads();
      row_pass(v3s);
      __syncthreads();
      if (t < nr) wrow[t] = 1.0 / v3s[t];
      __syncthreads();
      double a3 = alpha[t];
#pragma unroll 4
      for (int r = 0; r < nr; ++r)
        out[(size_t)(start + r) * KDIM + t] =
            (float)(a3 * (double)Et[r * KDIM + t] * wrow[r]);
      return;
    }

    // C: v3~, gv3~; allreduce (gdir, t3)
    alpha[t] = k2_t / u2_t;
    __syncthreads();
    {
      double a0 = alpha[4 * lane + 0], a1 = alpha[4 * lane + 1];
      double a2 = alpha[4 * lane + 2], a3 = alpha[4 * lane + 3];
      for (int r = wv; r < nr; r += 4) {
        float4 e4 = ((const float4*)(Et + r * KDIM))[lane];
        float4 f4 = ((const float4*)(Ft + r * KDIM))[lane];
        double p0 = a0 * (double)e4.x, p1 = a1 * (double)e4.y;
        double p2 = a2 * (double)e4.z, p3 = a3 * (double)e4.w;
        double s1 = p0 + p1 + p2 + p3;
        double s2 = p0 * (double)f4.x + p1 * (double)f4.y +
                    p2 * (double)f4.z + p3 * (double)f4.w;
        s1 = wave_sum_d(s1);
        s2 = wave_sum_d(s2);
        if (lane == 0) {
          v3s[r] = s1;
          grow[r] = s2 / (16384.0 * s1 * s1);  // gv3~
        }
      }
    }
    __syncthreads();
    if (t < nr) wrow[t] = -1.0 / (16384.0 * v3s[t]);
    __syncthreads();
    double gd_t, t3_t;
    {
      double ac1 = 0.0, ac2 = 0.0;
#pragma unroll 4
      for (int r = 0; r < nr; ++r) {
        double ed = (double)Et[r * KDIM + t];
        ac1 += ed * (double)Ft[r * KDIM + t] * wrow[r];
        ac2 += ed * grow[r];
      }
      ++ph; w_allreduce(ph, true, ac1, ac2, gd_t, t3_t);
    }

    // D: gu2 -> gv2~; allreduce ga2
    alpha[t] = -(gd_t + t3_t) * k2_t / (u2_t * u2_t);
    __syncthreads();
    row_pass(grow);
    __syncthreads();
    if (t < nr) wrow[t] = -grow[t] / (16384.0 * v2s[t] * v2s[t]);
    __syncthreads();
    double ga2_t;
    { double pa = col_partial(); ++ph; w_allreduce(ph, false, pa, 0.0, ga2_t, dmy); }

    // E: gu1 -> gv1~; allreduce ga1
    alpha[t] = -ga2_t * k2_t / (u1_t * u1_t);
    __syncthreads();
    row_pass(grow);
    __syncthreads();
    if (t < nr) wrow[t] = -grow[t] / (16384.0 * v1s[t] * v1s[t]);
    __syncthreads();
    double ga1_t;
    { double pa = col_partial(); ++ph; w_allreduce(ph, false, pa, 0.0, ga1_t, dmy); }

    // F: replicated optimizer step (block-local; blk_sum's barrier drains QN)
    {
      double gk2 = (gd_t + t3_t) / u2_t + ga2_t / u1_t + ga1_t / u0_t;
      double dot = blk_sum(k2_t * gk2);
      double gw = k2_t * (gk2 - dot) + 5.0 * (k2_t / 256.0 - 1.0 / 65536.0);
      double n2 = blk_sum(gw * gw);
      float normf = (float)sqrt(n2);
      float sc = fminf(1.0f, 1.0f / (normf + 1e-6f));
      float g = (float)gw * sc;
      buf_t = 0.99f * buf_t + g;
      w_t = w_t - 0.1f * buf_t;
      double x = (double)w_t;
      double m = blk_max(x);
      double e = fast_exp_d(x - m);
      double s = blk_sum(e);
      k2_t = e / s;
    }
  }
}

// ---------------------------------------------------------------------------
extern "C" void kernel_launch(void* const* d_in, const int* in_sizes, int n_in,
                              void* d_out, int out_size, void* d_ws,
                              size_t ws_size, hipStream_t stream) {
  (void)in_sizes; (void)n_in; (void)out_size; (void)ws_size;
  const float* feat = (const float*)d_in[0];
  const float* w_in = (const float*)d_in[1];
  float* out = (float*)d_out;
  double* ws = (double*)d_ws;

  kInitWS<<<256, 256, 0, stream>>>(ws);
  sink_main<<<NBLK, 256, 0, stream>>>(feat, w_in, out, ws);
}